// Round 1
// baseline (4808.250 us; speedup 1.0000x reference)
//
#include <hip/hip_runtime.h>

#define NSEQ   5200   // B*N = 16*325
#define NNODE  325
#define LE     96     // encoder length
#define LD     144    // decoder length
#define DM     64
#define KP     65     // padded row stride for K/V in LDS
#define OUTL   48
#define NWAVES 8
#define NTHR   512

struct Params {
  const float* x_enc; const float* x_dec;
  const float* enc_conv_w; const float* dec_conv_w;
  const float* eWq; const float* ebq; const float* eWk; const float* ebk;
  const float* eWv; const float* ebv; const float* eWo; const float* ebo;
  const float* ec1_w; const float* ec1_b; const float* ec2_w; const float* ec2_b;
  const float* en1_g; const float* en1_b; const float* en2_g; const float* en2_b;
  const float* dWq; const float* dbq; const float* dWk; const float* dbk;
  const float* dWv; const float* dbv; const float* dWo; const float* dbo;
  const float* dc1_w; const float* dc1_b; const float* dc2_w; const float* dc2_b;
  const float* dn2_g; const float* dn2_b; const float* dn3_g; const float* dn3_b;
  const float* proj_w; const float* proj_b;
  float* out;
};

__device__ __forceinline__ float wave_sum(float v){
  v += __shfl_xor(v, 32, 64);
  v += __shfl_xor(v, 16, 64);
  v += __shfl_xor(v,  8, 64);
  v += __shfl_xor(v,  4, 64);
  v += __shfl_xor(v,  2, 64);
  v += __shfl_xor(v,  1, 64);
  return v;
}
__device__ __forceinline__ float wave_max(float v){
  v = fmaxf(v, __shfl_xor(v, 32, 64));
  v = fmaxf(v, __shfl_xor(v, 16, 64));
  v = fmaxf(v, __shfl_xor(v,  8, 64));
  v = fmaxf(v, __shfl_xor(v,  4, 64));
  v = fmaxf(v, __shfl_xor(v,  2, 64));
  v = fmaxf(v, __shfl_xor(v,  1, 64));
  return v;
}

// out[r][lane] = bias[lane] + sum_i in[r][i] * W[i][lane], written with stride KP.
// Weight column held in 64 VGPRs; input rows read as wave-broadcast float4.
__device__ __forceinline__ void proj_kv(const float* sIn, int rows, float* sOut,
                                        const float* __restrict__ W,
                                        const float* __restrict__ Bv,
                                        int wave, int lane)
{
  float wr[64];
  #pragma unroll
  for (int i = 0; i < 64; ++i) wr[i] = W[i*64 + lane];
  const float bias = Bv[lane];
  for (int r = wave; r < rows; r += NWAVES){
    const float4* x4 = (const float4*)(sIn + r*64);
    float acc = bias;
    #pragma unroll
    for (int i = 0; i < 16; ++i){
      float4 x = x4[i];
      acc += x.x*wr[4*i] + x.y*wr[4*i+1] + x.z*wr[4*i+2] + x.w*wr[4*i+3];
    }
    sOut[r*KP + lane] = acc;
  }
}

// Full single-head attention + output proj + residual + LayerNorm, in place on sX.
// Keys/values: 96 rows in sK/sV (stride KP). Per-wave scratch wbA[64], wbB[96].
__device__ __forceinline__ void attention(float* sX, int qrows,
                                          const float* sK, const float* sV,
                                          float* wbA, float* wbB,
                                          const float* __restrict__ Wq, const float* __restrict__ bq_,
                                          const float* __restrict__ Wo, const float* __restrict__ bo_,
                                          const float* __restrict__ g_, const float* __restrict__ b_,
                                          int wave, int lane)
{
  float wqr[64], wor[64];
  #pragma unroll
  for (int i = 0; i < 64; ++i){ wqr[i] = Wq[i*64 + lane]; wor[i] = Wo[i*64 + lane]; }
  const float bq = bq_[lane], bo = bo_[lane];
  const float gv = g_[lane],  bv = b_[lane];
  const float* krow0 = sK + lane * KP;
  const float* krow1 = sK + (64 + (lane & 31)) * KP;  // clamped; masked for lane>=32
  const bool hi = (lane < 32);

  for (int l = wave; l < qrows; l += NWAVES){
    // --- q row ---
    const float4* x4 = (const float4*)(sX + l*64);
    float q = bq;
    #pragma unroll
    for (int i = 0; i < 16; ++i){
      float4 x = x4[i];
      q += x.x*wqr[4*i] + x.y*wqr[4*i+1] + x.z*wqr[4*i+2] + x.w*wqr[4*i+3];
    }
    wbA[lane] = q;
    __threadfence_block();
    // --- scores: lane s covers key row s; lanes<32 also cover 64+s ---
    const float4* q4 = (const float4*)wbA;
    float s0 = 0.f, s1 = 0.f;
    #pragma unroll
    for (int i = 0; i < 16; ++i){
      float4 qq = q4[i];
      s0 += qq.x*krow0[4*i] + qq.y*krow0[4*i+1] + qq.z*krow0[4*i+2] + qq.w*krow0[4*i+3];
      s1 += qq.x*krow1[4*i] + qq.y*krow1[4*i+1] + qq.z*krow1[4*i+2] + qq.w*krow1[4*i+3];
    }
    float z0 = s0 * 0.125f;                       // scale = 1/sqrt(64)
    float z1 = hi ? s1 * 0.125f : -3.0e38f;
    float m  = wave_max(fmaxf(z0, z1));
    float e0 = __expf(z0 - m);
    float e1 = hi ? __expf(z1 - m) : 0.f;
    float rden = 1.f / wave_sum(e0 + e1);
    wbB[lane] = e0 * rden;
    if (hi) wbB[64 + lane] = e1 * rden;
    __threadfence_block();
    // --- context: o[lane] = sum_s p[s] * V[s][lane] ---
    const float4* p4 = (const float4*)wbB;
    const float* vcol = sV + lane;
    float o = 0.f;
    #pragma unroll
    for (int s = 0; s < 24; ++s){
      float4 pp = p4[s];
      o += pp.x*vcol[(4*s+0)*KP] + pp.y*vcol[(4*s+1)*KP]
         + pp.z*vcol[(4*s+2)*KP] + pp.w*vcol[(4*s+3)*KP];
    }
    wbA[lane] = o;
    __threadfence_block();
    // --- output proj + residual + LN ---
    const float4* o4 = (const float4*)wbA;
    float a = bo;
    #pragma unroll
    for (int i = 0; i < 16; ++i){
      float4 oo = o4[i];
      a += oo.x*wor[4*i] + oo.y*wor[4*i+1] + oo.z*wor[4*i+2] + oo.w*wor[4*i+3];
    }
    float xv = sX[l*64 + lane] + a;
    float mu = wave_sum(xv) * (1.f/64.f);
    float dd = xv - mu;
    float var = wave_sum(dd*dd) * (1.f/64.f);
    sX[l*64 + lane] = dd * rsqrtf(var + 1e-5f) * gv + bv;
    __threadfence_block();
  }
}

// Encoder FFN (dff = 64) + residual + LN, in place on sX.
__device__ __forceinline__ void ffn64(float* sX, int rows, float* wbA,
                                      const float* __restrict__ W1, const float* __restrict__ b1_,
                                      const float* __restrict__ W2, const float* __restrict__ b2_,
                                      const float* __restrict__ g_, const float* __restrict__ b_,
                                      int wave, int lane)
{
  float w1r[64], w2r[64];
  #pragma unroll
  for (int i = 0; i < 64; ++i){ w1r[i] = W1[i*64 + lane]; w2r[i] = W2[i*64 + lane]; }
  const float b1 = b1_[lane], b2 = b2_[lane];
  const float gv = g_[lane],  bv = b_[lane];
  for (int l = wave; l < rows; l += NWAVES){
    const float4* x4 = (const float4*)(sX + l*64);
    float h = b1;
    #pragma unroll
    for (int i = 0; i < 16; ++i){
      float4 x = x4[i];
      h += x.x*w1r[4*i] + x.y*w1r[4*i+1] + x.z*w1r[4*i+2] + x.w*w1r[4*i+3];
    }
    h = fmaxf(h, 0.f);
    wbA[lane] = h;
    __threadfence_block();
    const float4* h4 = (const float4*)wbA;
    float y = b2;
    #pragma unroll
    for (int i = 0; i < 16; ++i){
      float4 hh = h4[i];
      y += hh.x*w2r[4*i] + hh.y*w2r[4*i+1] + hh.z*w2r[4*i+2] + hh.w*w2r[4*i+3];
    }
    float xv = sX[l*64 + lane] + y;
    float mu = wave_sum(xv) * (1.f/64.f);
    float dd = xv - mu;
    float var = wave_sum(dd*dd) * (1.f/64.f);
    sX[l*64 + lane] = dd * rsqrtf(var + 1e-5f) * gv + bv;
    __threadfence_block();
  }
}

__global__ void __launch_bounds__(NTHR, 1)
GraphTransformer_90237262889124_kernel(Params p)
{
  extern __shared__ __align__(16) float lds[];
  float* sA    = lds;            // 9216: decoder activations (144x64)
  float* sK    = sA + 9216;      // 6240: keys   (96 x KP)
  float* sV    = sK + 6240;      // 6240: values (96 x KP)
  float* sE    = sV + 6240;      // 6144: encoder activations (96x64)
  float* ser   = sE + 6144;      // 144: raw series
  float* stat  = ser + 144;      // [0]=enc mean, [1]=dec mean
  float* wbufA = stat + 4;       // 8*64 per-wave scratch
  float* wbufB = wbufA + NWAVES*64; // 8*96 per-wave scratch
  float* sY    = sK;             // alias: FFN accumulator 144x64 (K,V dead by then)

  const int tid = threadIdx.x, lane = tid & 63, wave = tid >> 6;
  const int bn = blockIdx.x;
  const int b = bn / NNODE, n = bn % NNODE;
  float* wbA = wbufA + wave*64;
  float* wbB = wbufB + wave*96;

  // ---------------- encoder ----------------
  // E0: load series, subtract mean over L
  if (tid < LE) ser[tid] = p.x_enc[(b*LE + tid)*NNODE + n];
  __syncthreads();
  if (wave == 0){
    float v = ser[lane] + (lane < 32 ? ser[64 + lane] : 0.f);
    float s = wave_sum(v);
    if (lane == 0) stat[0] = s * (1.f/96.f);
  }
  __syncthreads();
  if (tid < LE) ser[tid] -= stat[0];
  __syncthreads();
  // E1: circular conv1d(k=3) -> sE
  {
    float c0 = p.enc_conv_w[lane*3+0], c1 = p.enc_conv_w[lane*3+1], c2 = p.enc_conv_w[lane*3+2];
    for (int l = wave; l < LE; l += NWAVES){
      int lm = (l == 0)    ? LE-1 : l-1;
      int lp = (l == LE-1) ? 0    : l+1;
      sE[l*64 + lane] = c0*ser[lm] + c1*ser[l] + c2*ser[lp];
    }
  }
  __syncthreads();
  // E2: k, v
  proj_kv(sE, LE, sK, p.eWk, p.ebk, wave, lane);
  proj_kv(sE, LE, sV, p.eWv, p.ebv, wave, lane);
  __syncthreads();
  // E3: self-attention + LN1 (in place)
  attention(sE, LE, sK, sV, wbA, wbB, p.eWq, p.ebq, p.eWo, p.ebo,
            p.en1_g, p.en1_b, wave, lane);
  __syncthreads();
  // E4: FFN(d->d) + LN2  => enc_out in sE
  ffn64(sE, LE, wbA, p.ec1_w, p.ec1_b, p.ec2_w, p.ec2_b, p.en2_g, p.en2_b, wave, lane);
  __syncthreads();

  // ---------------- decoder ----------------
  // D0: load series, subtract mean of first OUTL from first OUTL
  if (tid < LD) ser[tid] = p.x_dec[(b*LD + tid)*NNODE + n];
  __syncthreads();
  if (wave == 0){
    float v = (lane < OUTL) ? ser[lane] : 0.f;
    float s = wave_sum(v);
    if (lane == 0) stat[1] = s * (1.f/48.f);
  }
  __syncthreads();
  if (tid < OUTL) ser[tid] -= stat[1];
  __syncthreads();
  // D1: circular conv -> sA
  {
    float c0 = p.dec_conv_w[lane*3+0], c1 = p.dec_conv_w[lane*3+1], c2 = p.dec_conv_w[lane*3+2];
    for (int l = wave; l < LD; l += NWAVES){
      int lm = (l == 0)    ? LD-1 : l-1;
      int lp = (l == LD-1) ? 0    : l+1;
      sA[l*64 + lane] = c0*ser[lm] + c1*ser[l] + c2*ser[lp];
    }
  }
  __syncthreads();
  // D2: cross k, v from enc_out
  proj_kv(sE, LE, sK, p.dWk, p.dbk, wave, lane);
  proj_kv(sE, LE, sV, p.dWv, p.dbv, wave, lane);
  __syncthreads();
  // D3: cross-attention + LN(dn2), in place on sA
  attention(sA, LD, sK, sV, wbA, wbB, p.dWq, p.dbq, p.dWo, p.dbo,
            p.dn2_g, p.dn2_b, wave, lane);
  __syncthreads();
  // D4: FFN(d->4d->d), chunked over 4 column blocks of 64; y accumulates in sY
  for (int idx = tid; idx < LD*64; idx += NTHR) sY[idx] = 0.f;
  __syncthreads();
  for (int cc = 0; cc < 4; ++cc){
    float w1r[64], w2r[64];
    #pragma unroll
    for (int i = 0; i < 64; ++i){
      w1r[i] = p.dc1_w[i*256 + cc*64 + lane];
      w2r[i] = p.dc2_w[(cc*64 + i)*64 + lane];
    }
    float b1 = p.dc1_b[cc*64 + lane];
    for (int r = wave; r < LD; r += NWAVES){
      const float4* x4 = (const float4*)(sA + r*64);
      float h = b1;
      #pragma unroll
      for (int i = 0; i < 16; ++i){
        float4 x = x4[i];
        h += x.x*w1r[4*i] + x.y*w1r[4*i+1] + x.z*w1r[4*i+2] + x.w*w1r[4*i+3];
      }
      h = fmaxf(h, 0.f);
      wbA[lane] = h;
      __threadfence_block();
      const float4* h4 = (const float4*)wbA;
      float y = 0.f;
      #pragma unroll
      for (int i = 0; i < 16; ++i){
        float4 hh = h4[i];
        y += hh.x*w2r[4*i] + hh.y*w2r[4*i+1] + hh.z*w2r[4*i+2] + hh.w*w2r[4*i+3];
      }
      sY[r*64 + lane] += y;
      __threadfence_block();
    }
  }
  __syncthreads();
  // final: LN(dn3) + projection + add enc mean, emit last OUTL rows
  {
    const float gv = p.dn3_g[lane], bv = p.dn3_b[lane];
    const float pw = p.proj_w[lane], b2c = p.dc2_b[lane];
    const float pb = p.proj_b[0], emean = stat[0];
    for (int r = wave; r < LD; r += NWAVES){
      float xv = sA[r*64 + lane] + sY[r*64 + lane] + b2c;
      float mu = wave_sum(xv) * (1.f/64.f);
      float dd = xv - mu;
      float var = wave_sum(dd*dd) * (1.f/64.f);
      float xn = dd * rsqrtf(var + 1e-5f) * gv + bv;
      float s = wave_sum(xn * pw);
      if (lane == 0 && r >= LD - OUTL)
        p.out[(b*OUTL + (r - (LD - OUTL)))*NNODE + n] = s + pb + emean;
    }
  }
}

extern "C" void kernel_launch(void* const* d_in, const int* in_sizes, int n_in,
                              void* d_out, int out_size, void* d_ws, size_t ws_size,
                              hipStream_t stream) {
  Params p;
  p.x_enc = (const float*)d_in[0];  p.x_dec = (const float*)d_in[1];
  // d_in[2] = adj_matrix (unused by reference), d_in[3] = out_len (static 48)
  p.enc_conv_w = (const float*)d_in[4];  p.dec_conv_w = (const float*)d_in[5];
  p.eWq = (const float*)d_in[6];   p.ebq = (const float*)d_in[7];
  p.eWk = (const float*)d_in[8];   p.ebk = (const float*)d_in[9];
  p.eWv = (const float*)d_in[10];  p.ebv = (const float*)d_in[11];
  p.eWo = (const float*)d_in[12];  p.ebo = (const float*)d_in[13];
  p.ec1_w = (const float*)d_in[14]; p.ec1_b = (const float*)d_in[15];
  p.ec2_w = (const float*)d_in[16]; p.ec2_b = (const float*)d_in[17];
  p.en1_g = (const float*)d_in[18]; p.en1_b = (const float*)d_in[19];
  p.en2_g = (const float*)d_in[20]; p.en2_b = (const float*)d_in[21];
  p.dWq = (const float*)d_in[22];  p.dbq = (const float*)d_in[23];
  p.dWk = (const float*)d_in[24];  p.dbk = (const float*)d_in[25];
  p.dWv = (const float*)d_in[26];  p.dbv = (const float*)d_in[27];
  p.dWo = (const float*)d_in[28];  p.dbo = (const float*)d_in[29];
  p.dc1_w = (const float*)d_in[30]; p.dc1_b = (const float*)d_in[31];
  p.dc2_w = (const float*)d_in[32]; p.dc2_b = (const float*)d_in[33];
  p.dn2_g = (const float*)d_in[34]; p.dn2_b = (const float*)d_in[35];
  p.dn3_g = (const float*)d_in[36]; p.dn3_b = (const float*)d_in[37];
  p.proj_w = (const float*)d_in[38]; p.proj_b = (const float*)d_in[39];
  p.out = (float*)d_out;

  const int lds_bytes = 29268 * 4;  // 117072 B (< 160 KiB LDS/CU, 1 block/CU)
  (void)hipFuncSetAttribute((const void*)GraphTransformer_90237262889124_kernel,
                            hipFuncAttributeMaxDynamicSharedMemorySize, lds_bytes);
  GraphTransformer_90237262889124_kernel<<<NSEQ, NTHR, lds_bytes, stream>>>(p);
}

// Round 2
// 789.750 us; speedup vs baseline: 6.0883x; 6.0883x over previous
//
#include <hip/hip_runtime.h>

typedef _Float16 h8 __attribute__((ext_vector_type(8)));
typedef float f4 __attribute__((ext_vector_type(4)));

#define MFMA16(a,b,c) __builtin_amdgcn_mfma_f32_16x16x32_f16((a),(b),(c),0,0,0)

#define NSEQ  5200   // B*N
#define NNODE 325
#define LE    96     // encoder rows (6 row-tiles)
#define LD    144
#define DLOC  48     // live decoder rows: 96..143 (3 row-tiles)
#define OUTL  48
#define NTHR  512
#define NW    8
#define SX    80     // halves stride, 64-wide activation rows (160B, 16B-mult)
#define SV    112    // halves stride, Vt rows (96 wide)
#define SP    104    // halves stride, per-wave slot rows (up to 96 wide)
#define SW    80     // halves stride, transposed weight rows
#define SY    65     // fp32 stride, decoder FFN accumulator

// LDS layout in halves (all region starts 16B-aligned)
#define XE_OFF   0        // Xe fp16 [96][80]
#define K_OFF    7680     // K  fp16 [96][80]
#define VT_OFF   15360    // Vt fp16 [64][112]
#define XD_OFF   22528    // Xd fp16 [48][80]  (decoder rows 96..143)
#define W1_OFF   26368    // Wt slot 1 [64][80]
#define W2_OFF   31488    // Wt slot 2 [64][80]
#define SLOT_OFF 36608    // per-wave slots 8 x [16][104]
#define MISC_OFF 49920    // fp32 ser[144] + stat[2]
#define LDS_BYTES 100480
// Y fp32 [48][65] aliases XE/K/VT region (dead during decoder FFN): 12480B < 45056B

struct Params {
  const float* x_enc; const float* x_dec;
  const float* enc_conv_w; const float* dec_conv_w;
  const float* eWq; const float* ebq; const float* eWk; const float* ebk;
  const float* eWv; const float* ebv; const float* eWo; const float* ebo;
  const float* ec1_w; const float* ec1_b; const float* ec2_w; const float* ec2_b;
  const float* en1_g; const float* en1_b; const float* en2_g; const float* en2_b;
  const float* dWq; const float* dbq; const float* dWk; const float* dbk;
  const float* dWv; const float* dbv; const float* dWo; const float* dbo;
  const float* dc1_w; const float* dc1_b; const float* dc2_w; const float* dc2_b;
  const float* dn2_g; const float* dn2_b; const float* dn3_g; const float* dn3_b;
  const float* proj_w; const float* proj_b;
  float* out;
};

__device__ __forceinline__ float wave_sum(float v){
  v += __shfl_xor(v, 32, 64); v += __shfl_xor(v, 16, 64);
  v += __shfl_xor(v,  8, 64); v += __shfl_xor(v,  4, 64);
  v += __shfl_xor(v,  2, 64); v += __shfl_xor(v,  1, 64);
  return v;
}

// 16-lane (column-group) reductions for C-layout rows
__device__ __forceinline__ float red16_sum(float v){
  v += __shfl_xor(v,1,64); v += __shfl_xor(v,2,64);
  v += __shfl_xor(v,4,64); v += __shfl_xor(v,8,64);
  return v;
}
__device__ __forceinline__ float red16_max(float v){
  v = fmaxf(v,__shfl_xor(v,1,64)); v = fmaxf(v,__shfl_xor(v,2,64));
  v = fmaxf(v,__shfl_xor(v,4,64)); v = fmaxf(v,__shfl_xor(v,8,64));
  return v;
}

// transpose-load fp32 W[64][64] -> Wt[n][k] fp16 (stride SW)
__device__ __forceinline__ void loadWT(const float* __restrict__ W, _Float16* Wt, int tid){
  for (int i = tid; i < 4096; i += NTHR){
    int k = i >> 6, nn = i & 63;
    Wt[nn*SW + k] = (_Float16)W[i];
  }
}
// dc1 chunk: Wt[n][k] = dc1[k][cc*64+n]   (dc1 is [64][256])
__device__ __forceinline__ void loadWT_dc1(const float* __restrict__ W, int cc, _Float16* Wt, int tid){
  for (int i = tid; i < 4096; i += NTHR){
    int k = i >> 6, nn = i & 63;
    Wt[nn*SW + k] = (_Float16)W[k*256 + cc*64 + nn];
  }
}
// dc2 chunk: Wt[n][k] = dc2[cc*64+k][n]   (dc2 is [256][64])
__device__ __forceinline__ void loadWT_dc2(const float* __restrict__ W, int cc, _Float16* Wt, int tid){
  for (int i = tid; i < 4096; i += NTHR){
    int k = i >> 6, nn = i & 63;
    Wt[nn*SW + k] = (_Float16)W[(cc*64 + k)*64 + nn];
  }
}

// C[16x64] = Xrows[r0..r0+16) @ W (Wt transposed fp16, K=64), 8 MFMAs
__device__ __forceinline__ void mm64(const _Float16* X, int sx, int r0,
                                     const _Float16* Wt, f4 out[4], int m, int q){
  h8 a0 = *(const h8*)(X + (r0+m)*sx + q*8);
  h8 a1 = *(const h8*)(X + (r0+m)*sx + 32 + q*8);
  #pragma unroll
  for (int nt = 0; nt < 4; ++nt){
    h8 b0 = *(const h8*)(Wt + (nt*16+m)*SW + q*8);
    h8 b1 = *(const h8*)(Wt + (nt*16+m)*SW + 32 + q*8);
    f4 c = {0.f,0.f,0.f,0.f};
    c = MFMA16(a0, b0, c);
    c = MFMA16(a1, b1, c);
    out[nt] = c;
  }
}

// LayerNorm over 64 cols of C-layout rows, then store fp16 to X rows
__device__ __forceinline__ void ln16_store(float vf[4][4], _Float16* X, int sx, int r0,
                                           const float gv[4], const float bv[4], int m, int q){
  #pragma unroll
  for (int i = 0; i < 4; ++i){
    float s = vf[0][i] + vf[1][i] + vf[2][i] + vf[3][i];
    s = red16_sum(s);
    float mu = s * (1.f/64.f);
    float d0 = vf[0][i]-mu, d1 = vf[1][i]-mu, d2 = vf[2][i]-mu, d3 = vf[3][i]-mu;
    float vv = d0*d0 + d1*d1 + d2*d2 + d3*d3;
    vv = red16_sum(vv);
    float rs = rsqrtf(vv * (1.f/64.f) + 1e-5f);
    int ro = (r0 + q*4 + i)*sx + m;
    X[ro]      = (_Float16)(d0*rs*gv[0] + bv[0]);
    X[ro + 16] = (_Float16)(d1*rs*gv[1] + bv[1]);
    X[ro + 32] = (_Float16)(d2*rs*gv[2] + bv[2]);
    X[ro + 48] = (_Float16)(d3*rs*gv[3] + bv[3]);
  }
}

// build K rows (+bias) from src rows via Wt
__device__ __forceinline__ void build_K(const _Float16* src, _Float16* K,
                                        const _Float16* Wt, const float* __restrict__ bias,
                                        int wave, int m, int q){
  float bb[4];
  #pragma unroll
  for (int nt = 0; nt < 4; ++nt) bb[nt] = bias[nt*16 + m];
  for (int rt = wave; rt < 6; rt += NW){
    f4 c[4]; mm64(src, SX, rt*16, Wt, c, m, q);
    #pragma unroll
    for (int nt = 0; nt < 4; ++nt)
      #pragma unroll
      for (int i = 0; i < 4; ++i)
        K[(rt*16 + q*4 + i)*SX + nt*16 + m] = (_Float16)(c[nt][i] + bb[nt]);
  }
}
// build V transposed: Vt[d][s]
__device__ __forceinline__ void build_Vt(const _Float16* src, _Float16* Vt,
                                         const _Float16* Wt, const float* __restrict__ bias,
                                         int wave, int m, int q){
  float bb[4];
  #pragma unroll
  for (int nt = 0; nt < 4; ++nt) bb[nt] = bias[nt*16 + m];
  for (int rt = wave; rt < 6; rt += NW){
    f4 c[4]; mm64(src, SX, rt*16, Wt, c, m, q);
    #pragma unroll
    for (int nt = 0; nt < 4; ++nt)
      #pragma unroll
      for (int i = 0; i < 4; ++i)
        Vt[(nt*16 + m)*SV + rt*16 + q*4 + i] = (_Float16)(c[nt][i] + bb[nt]);
  }
}

// attention over nrt query row-tiles of X (stride SX), keys K[96], values Vt, + LN
__device__ __forceinline__ void attn_tiles(_Float16* X, int nrt,
        const _Float16* K, const _Float16* Vt, _Float16* slot,
        const _Float16* Wqt, const float* __restrict__ bq,
        const _Float16* Wot, const float* __restrict__ bo,
        const float* __restrict__ g_, const float* __restrict__ b_,
        int wave, int m, int q){
  float bqv[4], bov[4], gv[4], bv[4];
  #pragma unroll
  for (int nt = 0; nt < 4; ++nt){
    int c = nt*16 + m;
    bqv[nt] = bq[c]; bov[nt] = bo[c]; gv[nt] = g_[c]; bv[nt] = b_[c];
  }
  for (int rt = wave; rt < nrt; rt += NW){
    int r0 = rt*16;
    // Q = X@Wq + bq -> slot (A-layout rows)
    f4 c[4]; mm64(X, SX, r0, Wqt, c, m, q);
    #pragma unroll
    for (int nt = 0; nt < 4; ++nt)
      #pragma unroll
      for (int i = 0; i < 4; ++i)
        slot[(q*4 + i)*SP + nt*16 + m] = (_Float16)(c[nt][i] + bqv[nt]);
    __threadfence_block();
    // S = Q @ K^T (6 key tiles)
    h8 a0 = *(const h8*)(slot + m*SP + q*8);
    h8 a1 = *(const h8*)(slot + m*SP + 32 + q*8);
    f4 s[6];
    #pragma unroll
    for (int st = 0; st < 6; ++st){
      h8 b0 = *(const h8*)(K + (st*16+m)*SX + q*8);
      h8 b1 = *(const h8*)(K + (st*16+m)*SX + 32 + q*8);
      f4 cc = {0.f,0.f,0.f,0.f};
      cc = MFMA16(a0, b0, cc);
      cc = MFMA16(a1, b1, cc);
      s[st] = cc;
    }
    // softmax rows -> P fp16 into slot (overwrites Q; reads already in regs)
    #pragma unroll
    for (int i = 0; i < 4; ++i){
      float z0 = s[0][i]*0.125f, z1 = s[1][i]*0.125f, z2 = s[2][i]*0.125f;
      float z3 = s[3][i]*0.125f, z4 = s[4][i]*0.125f, z5 = s[5][i]*0.125f;
      float mx = fmaxf(fmaxf(fmaxf(z0,z1),fmaxf(z2,z3)),fmaxf(z4,z5));
      mx = red16_max(mx);
      z0 = __expf(z0-mx); z1 = __expf(z1-mx); z2 = __expf(z2-mx);
      z3 = __expf(z3-mx); z4 = __expf(z4-mx); z5 = __expf(z5-mx);
      float sm = z0+z1+z2+z3+z4+z5;
      sm = red16_sum(sm);
      float r = 1.f/sm;
      int ro = (q*4 + i)*SP + m;
      slot[ro]      = (_Float16)(z0*r); slot[ro + 16] = (_Float16)(z1*r);
      slot[ro + 32] = (_Float16)(z2*r); slot[ro + 48] = (_Float16)(z3*r);
      slot[ro + 64] = (_Float16)(z4*r); slot[ro + 80] = (_Float16)(z5*r);
    }
    __threadfence_block();
    // O = P @ V   (K dim = 96 -> 3 chunks)
    h8 pa0 = *(const h8*)(slot + m*SP + q*8);
    h8 pa1 = *(const h8*)(slot + m*SP + 32 + q*8);
    h8 pa2 = *(const h8*)(slot + m*SP + 64 + q*8);
    f4 o[4];
    #pragma unroll
    for (int nt = 0; nt < 4; ++nt){
      f4 cc = {0.f,0.f,0.f,0.f};
      cc = MFMA16(pa0, *(const h8*)(Vt + (nt*16+m)*SV + q*8), cc);
      cc = MFMA16(pa1, *(const h8*)(Vt + (nt*16+m)*SV + 32 + q*8), cc);
      cc = MFMA16(pa2, *(const h8*)(Vt + (nt*16+m)*SV + 64 + q*8), cc);
      o[nt] = cc;
    }
    __threadfence_block();
    // O -> slot (A-layout), then O @ Wo
    #pragma unroll
    for (int nt = 0; nt < 4; ++nt)
      #pragma unroll
      for (int i = 0; i < 4; ++i)
        slot[(q*4 + i)*SP + nt*16 + m] = (_Float16)o[nt][i];
    __threadfence_block();
    f4 y[4]; mm64(slot, SP, 0, Wot, y, m, q);
    // residual + bias + LN -> X
    float vf[4][4];
    #pragma unroll
    for (int nt = 0; nt < 4; ++nt)
      #pragma unroll
      for (int i = 0; i < 4; ++i)
        vf[nt][i] = y[nt][i] + bov[nt] + (float)X[(r0 + q*4 + i)*SX + nt*16 + m];
    ln16_store(vf, X, SX, r0, gv, bv, m, q);
    __threadfence_block();
  }
}

// encoder FFN (d->d) + residual + LN
__device__ __forceinline__ void ffn_enc(_Float16* X, _Float16* slot,
        const _Float16* W1t, const float* __restrict__ b1,
        const _Float16* W2t, const float* __restrict__ b2,
        const float* __restrict__ g_, const float* __restrict__ b_,
        int wave, int m, int q){
  float b1v[4], b2v[4], gv[4], bv[4];
  #pragma unroll
  for (int nt = 0; nt < 4; ++nt){
    int c = nt*16 + m;
    b1v[nt] = b1[c]; b2v[nt] = b2[c]; gv[nt] = g_[c]; bv[nt] = b_[c];
  }
  for (int rt = wave; rt < 6; rt += NW){
    int r0 = rt*16;
    f4 c[4]; mm64(X, SX, r0, W1t, c, m, q);
    #pragma unroll
    for (int nt = 0; nt < 4; ++nt)
      #pragma unroll
      for (int i = 0; i < 4; ++i)
        slot[(q*4 + i)*SP + nt*16 + m] = (_Float16)fmaxf(c[nt][i] + b1v[nt], 0.f);
    __threadfence_block();
    f4 y[4]; mm64(slot, SP, 0, W2t, y, m, q);
    float vf[4][4];
    #pragma unroll
    for (int nt = 0; nt < 4; ++nt)
      #pragma unroll
      for (int i = 0; i < 4; ++i)
        vf[nt][i] = y[nt][i] + b2v[nt] + (float)X[(r0 + q*4 + i)*SX + nt*16 + m];
    ln16_store(vf, X, SX, r0, gv, bv, m, q);
    __threadfence_block();
  }
}

__global__ void __launch_bounds__(NTHR, 1)
GraphTransformer_90237262889124_kernel(Params p)
{
  extern __shared__ __align__(16) _Float16 lds[];
  _Float16* Xe   = lds + XE_OFF;
  _Float16* K    = lds + K_OFF;
  _Float16* Vt   = lds + VT_OFF;
  _Float16* Xd   = lds + XD_OFF;
  _Float16* W1   = lds + W1_OFF;
  _Float16* W2   = lds + W2_OFF;
  float*    Y    = (float*)lds;                 // aliases Xe/K/Vt during dec FFN
  float*    ser  = (float*)(lds + MISC_OFF);    // 144 fp32
  float*    stat = ser + 144;

  const int tid = threadIdx.x, lane = tid & 63, wave = tid >> 6;
  const int m = lane & 15, q = lane >> 4;
  const int b = blockIdx.x / NNODE, n = blockIdx.x % NNODE;
  _Float16* slot = lds + SLOT_OFF + wave * 16 * SP;

  // ================= encoder =================
  if (tid < LE) ser[tid] = p.x_enc[(b*LE + tid)*NNODE + n];
  __syncthreads();
  if (wave == 0){
    float v = ser[lane] + (lane < 32 ? ser[64 + lane] : 0.f);
    float s = wave_sum(v);
    if (lane == 0) stat[0] = s * (1.f/96.f);
  }
  __syncthreads();
  if (tid < LE) ser[tid] -= stat[0];
  __syncthreads();
  {
    float c0 = p.enc_conv_w[lane*3+0], c1 = p.enc_conv_w[lane*3+1], c2 = p.enc_conv_w[lane*3+2];
    for (int l = wave; l < LE; l += NW){
      int lm = l ? l-1 : LE-1;
      int lp = (l == LE-1) ? 0 : l+1;
      Xe[l*SX + lane] = (_Float16)(c0*ser[lm] + c1*ser[l] + c2*ser[lp]);
    }
  }
  loadWT(p.eWk, W1, tid);
  loadWT(p.eWv, W2, tid);
  __syncthreads();                 // conv + weights visible
  build_K (Xe, K,  W1, p.ebk, wave, m, q);
  build_Vt(Xe, Vt, W2, p.ebv, wave, m, q);
  __syncthreads();
  loadWT(p.eWq, W1, tid);
  loadWT(p.eWo, W2, tid);
  __syncthreads();
  attn_tiles(Xe, 6, K, Vt, slot, W1, p.ebq, W2, p.ebo, p.en1_g, p.en1_b, wave, m, q);
  __syncthreads();
  loadWT(p.ec1_w, W1, tid);
  loadWT(p.ec2_w, W2, tid);
  __syncthreads();
  ffn_enc(Xe, slot, W1, p.ec1_b, W2, p.ec2_b, p.en2_g, p.en2_b, wave, m, q);
  __syncthreads();

  // ================= decoder =================
  if (tid < LD) ser[tid] = p.x_dec[(b*LD + tid)*NNODE + n];
  __syncthreads();
  if (wave == 0){
    float v = (lane < OUTL) ? ser[lane] : 0.f;
    float s = wave_sum(v);
    if (lane == 0) stat[1] = s * (1.f/48.f);
  }
  __syncthreads();
  if (tid < OUTL) ser[tid] -= stat[1];
  __syncthreads();
  // circular conv, live rows 96..143 only (row-local after this point)
  {
    float c0 = p.dec_conv_w[lane*3+0], c1 = p.dec_conv_w[lane*3+1], c2 = p.dec_conv_w[lane*3+2];
    for (int l = wave; l < DLOC; l += NW){
      int gr = 96 + l;
      int lm = gr - 1;
      int lp = (gr == LD-1) ? 0 : gr + 1;
      Xd[l*SX + lane] = (_Float16)(c0*ser[lm] + c1*ser[gr] + c2*ser[lp]);
    }
  }
  loadWT(p.dWk, W1, tid);
  loadWT(p.dWv, W2, tid);
  __syncthreads();
  build_K (Xe, K,  W1, p.dbk, wave, m, q);   // cross K/V from enc_out
  build_Vt(Xe, Vt, W2, p.dbv, wave, m, q);
  __syncthreads();
  loadWT(p.dWq, W1, tid);
  loadWT(p.dWo, W2, tid);
  __syncthreads();
  attn_tiles(Xd, 3, K, Vt, slot, W1, p.dbq, W2, p.dbo, p.dn2_g, p.dn2_b, wave, m, q);
  __syncthreads();
  // decoder FFN (d -> 4d -> d), chunked over 4 blocks of 64 hidden cols
  for (int i = tid; i < DLOC*SY; i += NTHR) Y[i] = 0.f;   // Xe/K/Vt now dead
  for (int cc = 0; cc < 4; ++cc){
    __syncthreads();
    loadWT_dc1(p.dc1_w, cc, W1, tid);
    loadWT_dc2(p.dc2_w, cc, W2, tid);
    __syncthreads();
    float b1v[4];
    #pragma unroll
    for (int nt = 0; nt < 4; ++nt) b1v[nt] = p.dc1_b[cc*64 + nt*16 + m];
    for (int rt = wave; rt < 3; rt += NW){
      int r0 = rt*16;
      f4 c[4]; mm64(Xd, SX, r0, W1, c, m, q);
      #pragma unroll
      for (int nt = 0; nt < 4; ++nt)
        #pragma unroll
        for (int i = 0; i < 4; ++i)
          slot[(q*4 + i)*SP + nt*16 + m] = (_Float16)fmaxf(c[nt][i] + b1v[nt], 0.f);
      __threadfence_block();
      f4 y[4]; mm64(slot, SP, 0, W2, y, m, q);
      #pragma unroll
      for (int nt = 0; nt < 4; ++nt)
        #pragma unroll
        for (int i = 0; i < 4; ++i)
          Y[(r0 + q*4 + i)*SY + nt*16 + m] += y[nt][i];
      __threadfence_block();
    }
  }
  __syncthreads();
  // final LN(dn3) + projection + add enc mean
  {
    const float gv = p.dn3_g[lane], bvv = p.dn3_b[lane];
    const float pw = p.proj_w[lane], b2c = p.dc2_b[lane];
    const float pb = p.proj_b[0], emean = stat[0];
    for (int rl = wave; rl < DLOC; rl += NW){
      float xv = (float)Xd[rl*SX + lane] + Y[rl*SY + lane] + b2c;
      float mu = wave_sum(xv) * (1.f/64.f);
      float dd = xv - mu;
      float var = wave_sum(dd*dd) * (1.f/64.f);
      float xn = dd * rsqrtf(var + 1e-5f) * gv + bvv;
      float s = wave_sum(xn * pw);
      if (lane == 0)
        p.out[(b*OUTL + rl)*NNODE + n] = s + pb + emean;
    }
  }
}

extern "C" void kernel_launch(void* const* d_in, const int* in_sizes, int n_in,
                              void* d_out, int out_size, void* d_ws, size_t ws_size,
                              hipStream_t stream) {
  Params p;
  p.x_enc = (const float*)d_in[0];  p.x_dec = (const float*)d_in[1];
  p.enc_conv_w = (const float*)d_in[4];  p.dec_conv_w = (const float*)d_in[5];
  p.eWq = (const float*)d_in[6];   p.ebq = (const float*)d_in[7];
  p.eWk = (const float*)d_in[8];   p.ebk = (const float*)d_in[9];
  p.eWv = (const float*)d_in[10];  p.ebv = (const float*)d_in[11];
  p.eWo = (const float*)d_in[12];  p.ebo = (const float*)d_in[13];
  p.ec1_w = (const float*)d_in[14]; p.ec1_b = (const float*)d_in[15];
  p.ec2_w = (const float*)d_in[16]; p.ec2_b = (const float*)d_in[17];
  p.en1_g = (const float*)d_in[18]; p.en1_b = (const float*)d_in[19];
  p.en2_g = (const float*)d_in[20]; p.en2_b = (const float*)d_in[21];
  p.dWq = (const float*)d_in[22];  p.dbq = (const float*)d_in[23];
  p.dWk = (const float*)d_in[24];  p.dbk = (const float*)d_in[25];
  p.dWv = (const float*)d_in[26];  p.dbv = (const float*)d_in[27];
  p.dWo = (const float*)d_in[28];  p.dbo = (const float*)d_in[29];
  p.dc1_w = (const float*)d_in[30]; p.dc1_b = (const float*)d_in[31];
  p.dc2_w = (const float*)d_in[32]; p.dc2_b = (const float*)d_in[33];
  p.dn2_g = (const float*)d_in[34]; p.dn2_b = (const float*)d_in[35];
  p.dn3_g = (const float*)d_in[36]; p.dn3_b = (const float*)d_in[37];
  p.proj_w = (const float*)d_in[38]; p.proj_b = (const float*)d_in[39];
  p.out = (float*)d_out;

  (void)hipFuncSetAttribute((const void*)GraphTransformer_90237262889124_kernel,
                            hipFuncAttributeMaxDynamicSharedMemorySize, LDS_BYTES);
  GraphTransformer_90237262889124_kernel<<<NSEQ, NTHR, LDS_BYTES, stream>>>(p);
}

// Round 3
// 578.480 us; speedup vs baseline: 8.3119x; 1.3652x over previous
//
#include <hip/hip_runtime.h>

typedef _Float16 h8 __attribute__((ext_vector_type(8)));
typedef _Float16 h4 __attribute__((ext_vector_type(4)));
typedef float f4 __attribute__((ext_vector_type(4)));

#define MFMA16(a,b,c) __builtin_amdgcn_mfma_f32_16x16x32_f16((a),(b),(c),0,0,0)

#define NSEQ  5200
#define NNODE 325
#define LE    96
#define LD    144
#define OUTL  48
#define NTHR  512

#define SXE   72    // halves stride: Xe, Xd, K rows (144 B, 16B-mult; 4-way max on writes)
#define SVT   104   // halves stride: Vt rows (96 wide)
#define SSL   104   // halves stride: per-wave slot rows

// LDS layout (halves)
#define XE_OFF   0                 // Xe [96][72] = 6912
#define K_OFF    6912              // K  [96][72] = 6912
#define VT_OFF   13824             // Vt [64][104] = 6656
#define XD_OFF   20480             // Xd [48][72] = 3456
#define SLOT_OFF 23936             // 8 x [16][104] = 13312
#define MISC_OFF 37248             // fp32: serE[96] serD[144] stat[4] = 244 floats
#define LDS_BYTES 75472            // x2 = 150,944 <= 160 KiB -> 2 blocks/CU

// ws layout (halves): 10 transposed 64x64 + dc1t[256][64] + dc2t[64][256]
#define WSQ(i)   ((i)*4096)
#define WS_DC1   40960
#define WS_DC2   57344
#define WS_TOTAL 73728   // 147,456 bytes

struct Params {
  const float* x_enc; const float* x_dec;
  const float* enc_conv_w; const float* dec_conv_w;
  const float* eWq; const float* ebq; const float* eWk; const float* ebk;
  const float* eWv; const float* ebv; const float* eWo; const float* ebo;
  const float* ec1_w; const float* ec1_b; const float* ec2_w; const float* ec2_b;
  const float* en1_g; const float* en1_b; const float* en2_g; const float* en2_b;
  const float* dWq; const float* dbq; const float* dWk; const float* dbk;
  const float* dWv; const float* dbv; const float* dWo; const float* dbo;
  const float* dc1_w; const float* dc1_b; const float* dc2_w; const float* dc2_b;
  const float* dn2_g; const float* dn2_b; const float* dn3_g; const float* dn3_b;
  const float* proj_w; const float* proj_b;
  float* out;
};

__device__ __forceinline__ float wave_sum(float v){
  v += __shfl_xor(v, 32, 64); v += __shfl_xor(v, 16, 64);
  v += __shfl_xor(v,  8, 64); v += __shfl_xor(v,  4, 64);
  v += __shfl_xor(v,  2, 64); v += __shfl_xor(v,  1, 64);
  return v;
}
__device__ __forceinline__ float red16_sum(float v){
  v += __shfl_xor(v,1,64); v += __shfl_xor(v,2,64);
  v += __shfl_xor(v,4,64); v += __shfl_xor(v,8,64);
  return v;
}
__device__ __forceinline__ float red16_max(float v){
  v = fmaxf(v,__shfl_xor(v,1,64)); v = fmaxf(v,__shfl_xor(v,2,64));
  v = fmaxf(v,__shfl_xor(v,4,64)); v = fmaxf(v,__shfl_xor(v,8,64));
  return v;
}

// C[16x64] = X[r0..r0+16) @ W; B operand streamed from GLOBAL (pre-transposed fp16)
__device__ __forceinline__ void mm64g(const _Float16* X, int sx, int r0,
                                      const _Float16* __restrict__ Wt, int sw,
                                      f4 out[4], int m, int q){
  h8 a0 = *(const h8*)(X + (r0+m)*sx + q*8);
  h8 a1 = *(const h8*)(X + (r0+m)*sx + 32 + q*8);
  #pragma unroll
  for (int nt = 0; nt < 4; ++nt){
    h8 b0 = *(const h8*)(Wt + (nt*16+m)*sw + q*8);
    h8 b1 = *(const h8*)(Wt + (nt*16+m)*sw + 32 + q*8);
    f4 c = {0.f,0.f,0.f,0.f};
    c = MFMA16(a0, b0, c);
    c = MFMA16(a1, b1, c);
    out[nt] = c;
  }
}

// LN over 64 cols of C-layout rows -> fp16 store to X (stride sx)
__device__ __forceinline__ void ln16_store(float vf[4][4], _Float16* X, int sx, int r0,
                                           const float gv[4], const float bv[4], int m, int q){
  #pragma unroll
  for (int i = 0; i < 4; ++i){
    float s = vf[0][i] + vf[1][i] + vf[2][i] + vf[3][i];
    s = red16_sum(s);
    float mu = s * (1.f/64.f);
    float d0 = vf[0][i]-mu, d1 = vf[1][i]-mu, d2 = vf[2][i]-mu, d3 = vf[3][i]-mu;
    float vv = d0*d0 + d1*d1 + d2*d2 + d3*d3;
    vv = red16_sum(vv);
    float rs = rsqrtf(vv * (1.f/64.f) + 1e-5f);
    int ro = (r0 + q*4 + i)*sx + m;
    X[ro]      = (_Float16)(d0*rs*gv[0] + bv[0]);
    X[ro + 16] = (_Float16)(d1*rs*gv[1] + bv[1]);
    X[ro + 32] = (_Float16)(d2*rs*gv[2] + bv[2]);
    X[ro + 48] = (_Float16)(d3*rs*gv[3] + bv[3]);
  }
}

// one 16-row tile: K rows + Vt cols from src tile r0
__device__ __forceinline__ void build_kv_tile(const _Float16* src, int r0,
        _Float16* K, _Float16* Vt,
        const _Float16* __restrict__ Wkt, const float* __restrict__ bk,
        const _Float16* __restrict__ Wvt, const float* __restrict__ bv,
        int m, int q){
  f4 c[4];
  mm64g(src, SXE, r0, Wkt, 64, c, m, q);
  #pragma unroll
  for (int nt = 0; nt < 4; ++nt){
    float bb = bk[nt*16 + m];
    #pragma unroll
    for (int i = 0; i < 4; ++i)
      K[(r0 + q*4 + i)*SXE + nt*16 + m] = (_Float16)(c[nt][i] + bb);
  }
  mm64g(src, SXE, r0, Wvt, 64, c, m, q);
  #pragma unroll
  for (int nt = 0; nt < 4; ++nt){
    float bb = bv[nt*16 + m];
    h4 vv = { (_Float16)(c[nt][0]+bb), (_Float16)(c[nt][1]+bb),
              (_Float16)(c[nt][2]+bb), (_Float16)(c[nt][3]+bb) };
    *(h4*)(Vt + (nt*16+m)*SVT + r0 + q*4) = vv;   // contiguous b64 store
  }
  __threadfence_block();
}

// attention for one 16-row tile of X + LN (96 keys/values)
__device__ __forceinline__ void attn_tile(_Float16* X, int r0,
        const _Float16* K, const _Float16* Vt, _Float16* slot,
        const _Float16* __restrict__ Wqt, const float* __restrict__ bq,
        const _Float16* __restrict__ Wot, const float* __restrict__ bo,
        const float* __restrict__ g_, const float* __restrict__ b_,
        int m, int q){
  float bqv[4], bov[4], gv[4], bv[4];
  #pragma unroll
  for (int nt = 0; nt < 4; ++nt){
    int c = nt*16 + m;
    bqv[nt] = bq[c]; bov[nt] = bo[c]; gv[nt] = g_[c]; bv[nt] = b_[c];
  }
  // Q = X@Wq + bq -> slot (A layout)
  f4 c[4];
  mm64g(X, SXE, r0, Wqt, 64, c, m, q);
  #pragma unroll
  for (int nt = 0; nt < 4; ++nt)
    #pragma unroll
    for (int i = 0; i < 4; ++i)
      slot[(q*4 + i)*SSL + nt*16 + m] = (_Float16)(c[nt][i] + bqv[nt]);
  __threadfence_block();
  // S = Q @ K^T
  h8 a0 = *(const h8*)(slot + m*SSL + q*8);
  h8 a1 = *(const h8*)(slot + m*SSL + 32 + q*8);
  f4 s[6];
  #pragma unroll
  for (int st = 0; st < 6; ++st){
    h8 b0 = *(const h8*)(K + (st*16+m)*SXE + q*8);
    h8 b1 = *(const h8*)(K + (st*16+m)*SXE + 32 + q*8);
    f4 cc = {0.f,0.f,0.f,0.f};
    cc = MFMA16(a0, b0, cc);
    cc = MFMA16(a1, b1, cc);
    s[st] = cc;
  }
  // softmax -> P (fp16, overwrites Q in slot)
  #pragma unroll
  for (int i = 0; i < 4; ++i){
    float z0 = s[0][i]*0.125f, z1 = s[1][i]*0.125f, z2 = s[2][i]*0.125f;
    float z3 = s[3][i]*0.125f, z4 = s[4][i]*0.125f, z5 = s[5][i]*0.125f;
    float mx = fmaxf(fmaxf(fmaxf(z0,z1),fmaxf(z2,z3)),fmaxf(z4,z5));
    mx = red16_max(mx);
    z0 = __expf(z0-mx); z1 = __expf(z1-mx); z2 = __expf(z2-mx);
    z3 = __expf(z3-mx); z4 = __expf(z4-mx); z5 = __expf(z5-mx);
    float sm = red16_sum(z0+z1+z2+z3+z4+z5);
    float r = 1.f/sm;
    int ro = (q*4 + i)*SSL + m;
    slot[ro]      = (_Float16)(z0*r); slot[ro + 16] = (_Float16)(z1*r);
    slot[ro + 32] = (_Float16)(z2*r); slot[ro + 48] = (_Float16)(z3*r);
    slot[ro + 64] = (_Float16)(z4*r); slot[ro + 80] = (_Float16)(z5*r);
  }
  __threadfence_block();
  // O = P @ V
  h8 p0 = *(const h8*)(slot + m*SSL + q*8);
  h8 p1 = *(const h8*)(slot + m*SSL + 32 + q*8);
  h8 p2 = *(const h8*)(slot + m*SSL + 64 + q*8);
  f4 o[4];
  #pragma unroll
  for (int nt = 0; nt < 4; ++nt){
    f4 cc = {0.f,0.f,0.f,0.f};
    cc = MFMA16(p0, *(const h8*)(Vt + (nt*16+m)*SVT + q*8), cc);
    cc = MFMA16(p1, *(const h8*)(Vt + (nt*16+m)*SVT + 32 + q*8), cc);
    cc = MFMA16(p2, *(const h8*)(Vt + (nt*16+m)*SVT + 64 + q*8), cc);
    o[nt] = cc;
  }
  __threadfence_block();
  // O -> slot (A layout), then O @ Wo + residual + LN
  #pragma unroll
  for (int nt = 0; nt < 4; ++nt)
    #pragma unroll
    for (int i = 0; i < 4; ++i)
      slot[(q*4 + i)*SSL + nt*16 + m] = (_Float16)o[nt][i];
  __threadfence_block();
  f4 y[4];
  mm64g(slot, SSL, 0, Wot, 64, y, m, q);
  float vf[4][4];
  #pragma unroll
  for (int nt = 0; nt < 4; ++nt)
    #pragma unroll
    for (int i = 0; i < 4; ++i)
      vf[nt][i] = y[nt][i] + bov[nt] + (float)X[(r0 + q*4 + i)*SXE + nt*16 + m];
  ln16_store(vf, X, SXE, r0, gv, bv, m, q);
  __threadfence_block();
}

// encoder FFN (d->d) for one tile + LN
__device__ __forceinline__ void ffn_tile(_Float16* X, int r0, _Float16* slot,
        const _Float16* __restrict__ W1t, const float* __restrict__ b1,
        const _Float16* __restrict__ W2t, const float* __restrict__ b2,
        const float* __restrict__ g_, const float* __restrict__ b_,
        int m, int q){
  float b1v[4], b2v[4], gv[4], bv[4];
  #pragma unroll
  for (int nt = 0; nt < 4; ++nt){
    int c = nt*16 + m;
    b1v[nt] = b1[c]; b2v[nt] = b2[c]; gv[nt] = g_[c]; bv[nt] = b_[c];
  }
  f4 c[4];
  mm64g(X, SXE, r0, W1t, 64, c, m, q);
  #pragma unroll
  for (int nt = 0; nt < 4; ++nt)
    #pragma unroll
    for (int i = 0; i < 4; ++i)
      slot[(q*4 + i)*SSL + nt*16 + m] = (_Float16)fmaxf(c[nt][i] + b1v[nt], 0.f);
  __threadfence_block();
  f4 y[4];
  mm64g(slot, SSL, 0, W2t, 64, y, m, q);
  float vf[4][4];
  #pragma unroll
  for (int nt = 0; nt < 4; ++nt)
    #pragma unroll
    for (int i = 0; i < 4; ++i)
      vf[nt][i] = y[nt][i] + b2v[nt] + (float)X[(r0 + q*4 + i)*SXE + nt*16 + m];
  ln16_store(vf, X, SXE, r0, gv, bv, m, q);
  __threadfence_block();
}

// ---- weight prep: fp32 -> fp16 transposed, once per launch ----
__global__ void prep_weights(Params p, _Float16* ws){
  const float* sq[10] = {p.eWq, p.eWk, p.eWv, p.eWo, p.ec1_w, p.ec2_w,
                         p.dWq, p.dWk, p.dWv, p.dWo};
  for (int idx = blockIdx.x*blockDim.x + threadIdx.x; idx < WS_TOTAL;
       idx += gridDim.x*blockDim.x){
    if (idx < WS_DC1){
      int mi = idx >> 12, r = idx & 4095;
      int nn = r >> 6, k = r & 63;
      ws[idx] = (_Float16)sq[mi][k*64 + nn];          // Wt[n][k] = W[k][n]
    } else if (idx < WS_DC2){
      int r = idx - WS_DC1;                           // dc1t[n][k], n<256
      int nn = r >> 6, k = r & 63;
      ws[idx] = (_Float16)p.dc1_w[k*256 + nn];
    } else {
      int r = idx - WS_DC2;                           // dc2t[n][k2], stride 256
      int nn = r >> 8, k2 = r & 255;
      ws[idx] = (_Float16)p.dc2_w[k2*64 + nn];
    }
  }
}

__global__ void __launch_bounds__(NTHR, 4)
GraphTransformer_90237262889124_kernel(Params p, const _Float16* __restrict__ ws)
{
  extern __shared__ __align__(16) _Float16 lds[];
  _Float16* Xe   = lds + XE_OFF;
  _Float16* K    = lds + K_OFF;
  _Float16* Vt   = lds + VT_OFF;
  _Float16* Xd   = lds + XD_OFF;
  float*    serE = (float*)(lds + MISC_OFF);
  float*    serD = serE + 96;
  float*    stat = serD + 144;

  const int tid = threadIdx.x, lane = tid & 63, wave = tid >> 6;
  const int m = lane & 15, q = lane >> 4;
  const int b = blockIdx.x / NNODE, n = blockIdx.x % NNODE;
  _Float16* slot = lds + SLOT_OFF + wave * 16 * SSL;

  const _Float16* eWq_t = ws + WSQ(0);
  const _Float16* eWk_t = ws + WSQ(1);
  const _Float16* eWv_t = ws + WSQ(2);
  const _Float16* eWo_t = ws + WSQ(3);
  const _Float16* ec1_t = ws + WSQ(4);
  const _Float16* ec2_t = ws + WSQ(5);
  const _Float16* dWq_t = ws + WSQ(6);
  const _Float16* dWk_t = ws + WSQ(7);
  const _Float16* dWv_t = ws + WSQ(8);
  const _Float16* dWo_t = ws + WSQ(9);
  const _Float16* dc1t  = ws + WS_DC1;
  const _Float16* dc2t  = ws + WS_DC2;

  // ---- P0: series loads ----
  if (tid < LE)  serE[tid] = p.x_enc[(b*LE + tid)*NNODE + n];
  {
    int t2 = tid - 128;
    if (t2 >= 0 && t2 < LD) serD[t2] = p.x_dec[(b*LD + t2)*NNODE + n];
  }
  __syncthreads();                       // B1
  // ---- P1: means ----
  if (wave == 0){
    float v = serE[lane] + (lane < 32 ? serE[64 + lane] : 0.f);
    float s = wave_sum(v);
    if (lane == 0) stat[0] = s * (1.f/96.f);
  }
  if (wave == 1){
    float v = (lane < OUTL) ? serD[lane] : 0.f;
    float s = wave_sum(v);
    if (lane == 0) stat[1] = s * (1.f/48.f);
  }
  __syncthreads();                       // B2
  // ---- P2: conv (tile-local) + encoder K/V ----
  if (wave < 6){
    const float mu = stat[0];
    const float c0 = p.enc_conv_w[lane*3+0], c1 = p.enc_conv_w[lane*3+1], c2 = p.enc_conv_w[lane*3+2];
    const float cs = (c0 + c1 + c2) * mu;
    #pragma unroll
    for (int r = 0; r < 16; ++r){
      int l = wave*16 + r;
      int lm = l ? l-1 : LE-1;
      int lp = (l == LE-1) ? 0 : l+1;
      Xe[l*SXE + lane] = (_Float16)(c0*serE[lm] + c1*serE[l] + c2*serE[lp] - cs);
    }
    __threadfence_block();
    build_kv_tile(Xe, wave*16, K, Vt, eWk_t, p.ebk, eWv_t, p.ebv, m, q);
  } else {
    const float mu = stat[1];
    const float c0 = p.dec_conv_w[lane*3+0], c1 = p.dec_conv_w[lane*3+1], c2 = p.dec_conv_w[lane*3+2];
    for (int r = 0; r < 24; ++r){
      int l = (wave - 6)*24 + r;
      int gr = 96 + l;
      float xl = serD[gr-1];                                  // rows >= 95: no mean
      float xc = serD[gr];
      float xr = (gr == LD-1) ? (serD[0] - mu) : serD[gr+1];  // wrap to row 0 (mean-adj)
      Xd[l*SXE + lane] = (_Float16)(c0*xl + c1*xc + c2*xr);
    }
  }
  __syncthreads();                       // B3
  // ---- P3: encoder attention + FFN (tile-local, fused) ----
  if (wave < 6){
    attn_tile(Xe, wave*16, K, Vt, slot, eWq_t, p.ebq, eWo_t, p.ebo,
              p.en1_g, p.en1_b, m, q);
    ffn_tile(Xe, wave*16, slot, ec1_t, p.ec1_b, ec2_t, p.ec2_b,
             p.en2_g, p.en2_b, m, q);
  }
  __syncthreads();                       // B4
  // ---- P4: decoder cross K/V from enc_out ----
  if (wave < 6)
    build_kv_tile(Xe, wave*16, K, Vt, dWk_t, p.dbk, dWv_t, p.dbv, m, q);
  __syncthreads();                       // B5
  // ---- P5: decoder attention + FFN + LN + projection + store ----
  if (wave < 3){
    const int r0 = wave*16;
    attn_tile(Xd, r0, K, Vt, slot, dWq_t, p.dbq, dWo_t, p.dbo,
              p.dn2_g, p.dn2_b, m, q);
    // FFN d->4d->d, hidden chunked by 64; y accumulated in registers (C layout)
    f4 acc[4] = {{0.f,0.f,0.f,0.f},{0.f,0.f,0.f,0.f},{0.f,0.f,0.f,0.f},{0.f,0.f,0.f,0.f}};
    for (int cc = 0; cc < 4; ++cc){
      f4 h[4];
      mm64g(Xd, SXE, r0, dc1t + cc*4096, 64, h, m, q);
      #pragma unroll
      for (int nt = 0; nt < 4; ++nt){
        float bb = p.dc1_b[cc*64 + nt*16 + m];
        #pragma unroll
        for (int i = 0; i < 4; ++i)
          slot[(q*4 + i)*SSL + nt*16 + m] = (_Float16)fmaxf(h[nt][i] + bb, 0.f);
      }
      __threadfence_block();
      h8 a0 = *(const h8*)(slot + m*SSL + q*8);
      h8 a1 = *(const h8*)(slot + m*SSL + 32 + q*8);
      #pragma unroll
      for (int nt = 0; nt < 4; ++nt){
        h8 b0 = *(const h8*)(dc2t + (nt*16+m)*256 + cc*64 + q*8);
        h8 b1 = *(const h8*)(dc2t + (nt*16+m)*256 + cc*64 + 32 + q*8);
        acc[nt] = MFMA16(a0, b0, acc[nt]);
        acc[nt] = MFMA16(a1, b1, acc[nt]);
      }
      __threadfence_block();
    }
    // final LN(dn3) + proj + enc-mean
    float gvv[4], bvv[4], b2v[4], pwv[4];
    #pragma unroll
    for (int nt = 0; nt < 4; ++nt){
      int c = nt*16 + m;
      gvv[nt] = p.dn3_g[c]; bvv[nt] = p.dn3_b[c];
      b2v[nt] = p.dc2_b[c]; pwv[nt] = p.proj_w[c];
    }
    const float pb = p.proj_b[0], muE = stat[0];
    float vf[4][4];
    #pragma unroll
    for (int nt = 0; nt < 4; ++nt)
      #pragma unroll
      for (int i = 0; i < 4; ++i)
        vf[nt][i] = acc[nt][i] + b2v[nt] + (float)Xd[(r0 + q*4 + i)*SXE + nt*16 + m];
    #pragma unroll
    for (int i = 0; i < 4; ++i){
      float s = red16_sum(vf[0][i] + vf[1][i] + vf[2][i] + vf[3][i]);
      float mu = s * (1.f/64.f);
      float d0 = vf[0][i]-mu, d1 = vf[1][i]-mu, d2 = vf[2][i]-mu, d3 = vf[3][i]-mu;
      float vv = red16_sum(d0*d0 + d1*d1 + d2*d2 + d3*d3);
      float rs = rsqrtf(vv * (1.f/64.f) + 1e-5f);
      float pp = (d0*rs*gvv[0] + bvv[0])*pwv[0] + (d1*rs*gvv[1] + bvv[1])*pwv[1]
               + (d2*rs*gvv[2] + bvv[2])*pwv[2] + (d3*rs*gvv[3] + bvv[3])*pwv[3];
      pp = red16_sum(pp);
      if (m == 0)
        p.out[(b*OUTL + r0 + q*4 + i)*NNODE + n] = pp + pb + muE;
    }
  }
}

extern "C" void kernel_launch(void* const* d_in, const int* in_sizes, int n_in,
                              void* d_out, int out_size, void* d_ws, size_t ws_size,
                              hipStream_t stream) {
  Params p;
  p.x_enc = (const float*)d_in[0];  p.x_dec = (const float*)d_in[1];
  p.enc_conv_w = (const float*)d_in[4];  p.dec_conv_w = (const float*)d_in[5];
  p.eWq = (const float*)d_in[6];   p.ebq = (const float*)d_in[7];
  p.eWk = (const float*)d_in[8];   p.ebk = (const float*)d_in[9];
  p.eWv = (const float*)d_in[10];  p.ebv = (const float*)d_in[11];
  p.eWo = (const float*)d_in[12];  p.ebo = (const float*)d_in[13];
  p.ec1_w = (const float*)d_in[14]; p.ec1_b = (const float*)d_in[15];
  p.ec2_w = (const float*)d_in[16]; p.ec2_b = (const float*)d_in[17];
  p.en1_g = (const float*)d_in[18]; p.en1_b = (const float*)d_in[19];
  p.en2_g = (const float*)d_in[20]; p.en2_b = (const float*)d_in[21];
  p.dWq = (const float*)d_in[22];  p.dbq = (const float*)d_in[23];
  p.dWk = (const float*)d_in[24];  p.dbk = (const float*)d_in[25];
  p.dWv = (const float*)d_in[26];  p.dbv = (const float*)d_in[27];
  p.dWo = (const float*)d_in[28];  p.dbo = (const float*)d_in[29];
  p.dc1_w = (const float*)d_in[30]; p.dc1_b = (const float*)d_in[31];
  p.dc2_w = (const float*)d_in[32]; p.dc2_b = (const float*)d_in[33];
  p.dn2_g = (const float*)d_in[34]; p.dn2_b = (const float*)d_in[35];
  p.dn3_g = (const float*)d_in[36]; p.dn3_b = (const float*)d_in[37];
  p.proj_w = (const float*)d_in[38]; p.proj_b = (const float*)d_in[39];
  p.out = (float*)d_out;

  _Float16* ws = (_Float16*)d_ws;
  prep_weights<<<144, 512, 0, stream>>>(p, ws);

  (void)hipFuncSetAttribute((const void*)GraphTransformer_90237262889124_kernel,
                            hipFuncAttributeMaxDynamicSharedMemorySize, LDS_BYTES);
  GraphTransformer_90237262889124_kernel<<<NSEQ, NTHR, LDS_BYTES, stream>>>(p, ws);
}

// Round 4
// 544.904 us; speedup vs baseline: 8.8240x; 1.0616x over previous
//
#include <hip/hip_runtime.h>

typedef _Float16 h8 __attribute__((ext_vector_type(8)));
typedef _Float16 h4 __attribute__((ext_vector_type(4)));
typedef float f4 __attribute__((ext_vector_type(4)));

#define MFMA16(a,b,c) __builtin_amdgcn_mfma_f32_16x16x32_f16((a),(b),(c),0,0,0)
#define WB() __builtin_amdgcn_wave_barrier()   // compile-time order pin, 0 instr

#define NSEQ  5200
#define NNODE 325
#define LE    96
#define LD    144
#define OUTL  48
#define NTHR  384   // 6 waves: waves 0-5 own enc tiles 0-5; waves 0-2 own dec tiles
#define NW    6

#define SXE   72    // halves stride: K rows (144 B, 16B-mult)
#define SVT   104   // halves stride: Vt rows
#define SSL   104   // halves stride: per-wave slot rows

// LDS layout (halves); total 24,040 halves = 48,080 B -> 3 blocks/CU
#define K_OFF    0          // K  [96][72]  = 6912
#define VT_OFF   6912       // Vt [64][104] = 6656
#define SLOT_OFF 13568      // 6 x [16][104] = 9984
#define MISC_OFF 23552      // fp32 serE[96] serD[144] stat[4]
#define LDS_HALVES 24040

// ws layout (halves): 10 transposed 64x64 + dc1t[256][64] + dc2t[64][256]
#define WSQ(i)   ((i)*4096)
#define WS_DC1   40960
#define WS_DC2   57344
#define WS_TOTAL 73728

struct Params {
  const float* x_enc; const float* x_dec;
  const float* enc_conv_w; const float* dec_conv_w;
  const float* eWq; const float* ebq; const float* eWk; const float* ebk;
  const float* eWv; const float* ebv; const float* eWo; const float* ebo;
  const float* ec1_w; const float* ec1_b; const float* ec2_w; const float* ec2_b;
  const float* en1_g; const float* en1_b; const float* en2_g; const float* en2_b;
  const float* dWq; const float* dbq; const float* dWk; const float* dbk;
  const float* dWv; const float* dbv; const float* dWo; const float* dbo;
  const float* dc1_w; const float* dc1_b; const float* dc2_w; const float* dc2_b;
  const float* dn2_g; const float* dn2_b; const float* dn3_g; const float* dn3_b;
  const float* proj_w; const float* proj_b;
  float* out;
};

__device__ __forceinline__ float wave_sum(float v){
  v += __shfl_xor(v, 32, 64); v += __shfl_xor(v, 16, 64);
  v += __shfl_xor(v,  8, 64); v += __shfl_xor(v,  4, 64);
  v += __shfl_xor(v,  2, 64); v += __shfl_xor(v,  1, 64);
  return v;
}
__device__ __forceinline__ float red16_sum(float v){
  v += __shfl_xor(v,1,64); v += __shfl_xor(v,2,64);
  v += __shfl_xor(v,4,64); v += __shfl_xor(v,8,64);
  return v;
}
__device__ __forceinline__ float red16_max(float v){
  v = fmaxf(v,__shfl_xor(v,1,64)); v = fmaxf(v,__shfl_xor(v,2,64));
  v = fmaxf(v,__shfl_xor(v,4,64)); v = fmaxf(v,__shfl_xor(v,8,64));
  return v;
}

// C[16x64] = A(frags in regs) @ W; B streamed from global (pre-transposed fp16, stride 64)
__device__ __forceinline__ void mm64r(h8 a0, h8 a1,
                                      const _Float16* __restrict__ Wt,
                                      f4 out[4], int m, int q){
  #pragma unroll
  for (int nt = 0; nt < 4; ++nt){
    h8 b0 = *(const h8*)(Wt + (nt*16+m)*64 + q*8);
    h8 b1 = *(const h8*)(Wt + (nt*16+m)*64 + 32 + q*8);
    f4 c = {0.f,0.f,0.f,0.f};
    c = MFMA16(a0, b0, c);
    c = MFMA16(a1, b1, c);
    out[nt] = c;
  }
}

// store C-layout fp32 tile (+per-col add, optional relu) into slot as fp16
__device__ __forceinline__ void storeC16(_Float16* slot, const f4 c[4],
                                         const float add[4], bool relu, int m, int q){
  #pragma unroll
  for (int nt = 0; nt < 4; ++nt)
    #pragma unroll
    for (int i = 0; i < 4; ++i){
      float v = c[nt][i] + add[nt];
      if (relu) v = fmaxf(v, 0.f);
      slot[(q*4 + i)*SSL + nt*16 + m] = (_Float16)v;
    }
}
__device__ __forceinline__ void readA(const _Float16* slot, h8& a0, h8& a1, int m, int q){
  a0 = *(const h8*)(slot + m*SSL + q*8);
  a1 = *(const h8*)(slot + m*SSL + 32 + q*8);
}
__device__ __forceinline__ void readC(const _Float16* slot, h4 xc[4], int m, int q){
  #pragma unroll
  for (int nt = 0; nt < 4; ++nt){
    h4 t;
    #pragma unroll
    for (int i = 0; i < 4; ++i) t[i] = slot[(q*4 + i)*SSL + nt*16 + m];
    xc[nt] = t;
  }
}

// LN over 64 cols (C layout) -> slot fp16 + xc update
__device__ __forceinline__ void ln_slot(float vf[4][4], _Float16* slot, h4 xc[4],
        const float* __restrict__ g_, const float* __restrict__ b_, int m, int q){
  float gv[4], bv[4];
  #pragma unroll
  for (int nt = 0; nt < 4; ++nt){ gv[nt] = g_[nt*16+m]; bv[nt] = b_[nt*16+m]; }
  #pragma unroll
  for (int i = 0; i < 4; ++i){
    float s = red16_sum(vf[0][i] + vf[1][i] + vf[2][i] + vf[3][i]);
    float mu = s * (1.f/64.f);
    float d0 = vf[0][i]-mu, d1 = vf[1][i]-mu, d2 = vf[2][i]-mu, d3 = vf[3][i]-mu;
    float vv = red16_sum(d0*d0 + d1*d1 + d2*d2 + d3*d3);
    float rs = rsqrtf(vv * (1.f/64.f) + 1e-5f);
    int ro = (q*4 + i)*SSL + m;
    _Float16 n0 = (_Float16)(d0*rs*gv[0] + bv[0]);
    _Float16 n1 = (_Float16)(d1*rs*gv[1] + bv[1]);
    _Float16 n2 = (_Float16)(d2*rs*gv[2] + bv[2]);
    _Float16 n3 = (_Float16)(d3*rs*gv[3] + bv[3]);
    slot[ro] = n0; slot[ro+16] = n1; slot[ro+32] = n2; slot[ro+48] = n3;
    xc[0][i] = n0; xc[1][i] = n1; xc[2][i] = n2; xc[3][i] = n3;
  }
}

// attention + residual + LN; tile state (xa0,xa1,xc) in regs, updated in place
__device__ __forceinline__ void attn_reg(h8& xa0, h8& xa1, h4 xc[4], _Float16* slot,
        const _Float16* K, const _Float16* Vt,
        const _Float16* __restrict__ Wqt, const float* __restrict__ bq,
        const _Float16* __restrict__ Wot, const float* __restrict__ bo,
        const float* __restrict__ g_, const float* __restrict__ b_, int m, int q){
  f4 c[4];
  mm64r(xa0, xa1, Wqt, c, m, q);
  float bqv[4];
  #pragma unroll
  for (int nt = 0; nt < 4; ++nt) bqv[nt] = bq[nt*16+m];
  storeC16(slot, c, bqv, false, m, q);
  WB();
  h8 qa0, qa1; readA(slot, qa0, qa1, m, q);
  f4 s[6];
  #pragma unroll
  for (int st = 0; st < 6; ++st){
    h8 b0 = *(const h8*)(K + (st*16+m)*SXE + q*8);
    h8 b1 = *(const h8*)(K + (st*16+m)*SXE + 32 + q*8);
    f4 cc = {0.f,0.f,0.f,0.f};
    cc = MFMA16(qa0, b0, cc);
    cc = MFMA16(qa1, b1, cc);
    s[st] = cc;
  }
  WB();   // q-reads (row m) must precede P writes (rows q*4+i)
  #pragma unroll
  for (int i = 0; i < 4; ++i){
    float z0 = s[0][i]*0.125f, z1 = s[1][i]*0.125f, z2 = s[2][i]*0.125f;
    float z3 = s[3][i]*0.125f, z4 = s[4][i]*0.125f, z5 = s[5][i]*0.125f;
    float mx = fmaxf(fmaxf(fmaxf(z0,z1),fmaxf(z2,z3)),fmaxf(z4,z5));
    mx = red16_max(mx);
    z0 = __expf(z0-mx); z1 = __expf(z1-mx); z2 = __expf(z2-mx);
    z3 = __expf(z3-mx); z4 = __expf(z4-mx); z5 = __expf(z5-mx);
    float sm = red16_sum(z0+z1+z2+z3+z4+z5);
    float r = 1.f/sm;
    int ro = (q*4 + i)*SSL + m;
    slot[ro]      = (_Float16)(z0*r); slot[ro + 16] = (_Float16)(z1*r);
    slot[ro + 32] = (_Float16)(z2*r); slot[ro + 48] = (_Float16)(z3*r);
    slot[ro + 64] = (_Float16)(z4*r); slot[ro + 80] = (_Float16)(z5*r);
  }
  WB();
  h8 p0 = *(const h8*)(slot + m*SSL + q*8);
  h8 p1 = *(const h8*)(slot + m*SSL + 32 + q*8);
  h8 p2 = *(const h8*)(slot + m*SSL + 64 + q*8);
  f4 o[4];
  #pragma unroll
  for (int nt = 0; nt < 4; ++nt){
    f4 cc = {0.f,0.f,0.f,0.f};
    cc = MFMA16(p0, *(const h8*)(Vt + (nt*16+m)*SVT + q*8), cc);
    cc = MFMA16(p1, *(const h8*)(Vt + (nt*16+m)*SVT + 32 + q*8), cc);
    cc = MFMA16(p2, *(const h8*)(Vt + (nt*16+m)*SVT + 64 + q*8), cc);
    o[nt] = cc;
  }
  WB();   // p-reads precede O writes
  const float z4v[4] = {0.f,0.f,0.f,0.f};
  storeC16(slot, o, z4v, false, m, q);
  WB();
  h8 oa0, oa1; readA(slot, oa0, oa1, m, q);
  f4 y[4];
  mm64r(oa0, oa1, Wot, y, m, q);
  float vf[4][4];
  #pragma unroll
  for (int nt = 0; nt < 4; ++nt){
    float bb = bo[nt*16+m];
    #pragma unroll
    for (int i = 0; i < 4; ++i) vf[nt][i] = y[nt][i] + bb + (float)xc[nt][i];
  }
  ln_slot(vf, slot, xc, g_, b_, m, q);
  WB();
  readA(slot, xa0, xa1, m, q);
}

// FFN d->d + residual + LN; tile state updated in place
__device__ __forceinline__ void ffn_reg(h8& xa0, h8& xa1, h4 xc[4], _Float16* slot,
        const _Float16* __restrict__ W1t, const float* __restrict__ b1,
        const _Float16* __restrict__ W2t, const float* __restrict__ b2,
        const float* __restrict__ g_, const float* __restrict__ b_, int m, int q){
  f4 c[4];
  mm64r(xa0, xa1, W1t, c, m, q);
  float b1v[4];
  #pragma unroll
  for (int nt = 0; nt < 4; ++nt) b1v[nt] = b1[nt*16+m];
  storeC16(slot, c, b1v, true, m, q);
  WB();
  h8 ha0, ha1; readA(slot, ha0, ha1, m, q);
  f4 y[4];
  mm64r(ha0, ha1, W2t, y, m, q);
  float vf[4][4];
  #pragma unroll
  for (int nt = 0; nt < 4; ++nt){
    float bb = b2[nt*16+m];
    #pragma unroll
    for (int i = 0; i < 4; ++i) vf[nt][i] = y[nt][i] + bb + (float)xc[nt][i];
  }
  ln_slot(vf, slot, xc, g_, b_, m, q);
  WB();
  readA(slot, xa0, xa1, m, q);
}

// ---- weight prep: fp32 -> fp16 transposed, once per launch ----
__global__ void prep_weights(Params p, _Float16* ws){
  const float* sq[10] = {p.eWq, p.eWk, p.eWv, p.eWo, p.ec1_w, p.ec2_w,
                         p.dWq, p.dWk, p.dWv, p.dWo};
  for (int idx = blockIdx.x*blockDim.x + threadIdx.x; idx < WS_TOTAL;
       idx += gridDim.x*blockDim.x){
    if (idx < WS_DC1){
      int mi = idx >> 12, r = idx & 4095;
      int nn = r >> 6, k = r & 63;
      ws[idx] = (_Float16)sq[mi][k*64 + nn];
    } else if (idx < WS_DC2){
      int r = idx - WS_DC1;
      int nn = r >> 6, k = r & 63;
      ws[idx] = (_Float16)p.dc1_w[k*256 + nn];
    } else {
      int r = idx - WS_DC2;
      int nn = r >> 8, k2 = r & 255;
      ws[idx] = (_Float16)p.dc2_w[k2*64 + nn];
    }
  }
}

__global__ void __launch_bounds__(NTHR, 5)
GraphTransformer_90237262889124_kernel(Params p, const _Float16* __restrict__ ws)
{
  __shared__ __align__(16) _Float16 lds[LDS_HALVES];
  _Float16* K    = lds + K_OFF;
  _Float16* Vt   = lds + VT_OFF;
  float*    serE = (float*)(lds + MISC_OFF);
  float*    serD = serE + 96;
  float*    stat = serD + 144;

  const int tid = threadIdx.x, lane = tid & 63, wave = tid >> 6;
  const int m = lane & 15, q = lane >> 4;
  const int b = blockIdx.x / NNODE, n = blockIdx.x % NNODE;
  _Float16* slot = lds + SLOT_OFF + wave * 16 * SSL;

  const _Float16* eWq_t = ws + WSQ(0);
  const _Float16* eWk_t = ws + WSQ(1);
  const _Float16* eWv_t = ws + WSQ(2);
  const _Float16* eWo_t = ws + WSQ(3);
  const _Float16* ec1_t = ws + WSQ(4);
  const _Float16* ec2_t = ws + WSQ(5);
  const _Float16* dWq_t = ws + WSQ(6);
  const _Float16* dWk_t = ws + WSQ(7);
  const _Float16* dWv_t = ws + WSQ(8);
  const _Float16* dWo_t = ws + WSQ(9);
  const _Float16* dc1t  = ws + WS_DC1;
  const _Float16* dc2t  = ws + WS_DC2;

  // ---- P0: series loads ----
  if (tid < LE) serE[tid] = p.x_enc[(b*LE + tid)*NNODE + n];
  {
    int t2 = tid - 128;
    if (t2 >= 0 && t2 < LD) serD[t2] = p.x_dec[(b*LD + t2)*NNODE + n];
  }
  __syncthreads();                       // B1
  // ---- P1: means ----
  if (wave == 0){
    float v = serE[lane] + (lane < 32 ? serE[64 + lane] : 0.f);
    float s = wave_sum(v);
    if (lane == 0) stat[0] = s * (1.f/96.f);
  }
  if (wave == 1){
    float v = (lane < OUTL) ? serD[lane] : 0.f;
    float s = wave_sum(v);
    if (lane == 0) stat[1] = s * (1.f/48.f);
  }
  __syncthreads();                       // B2

  const int r0 = wave * 16;              // enc tile rows
  h8 xa0, xa1; h4 xc[4];
  // ---- P2: enc conv (via slot) -> regs; then K/V build ----
  {
    const float mu = stat[0];
    const float c0 = p.enc_conv_w[lane*3+0], c1 = p.enc_conv_w[lane*3+1], c2 = p.enc_conv_w[lane*3+2];
    const float cs = (c0 + c1 + c2) * mu;
    #pragma unroll
    for (int r = 0; r < 16; ++r){
      int l = r0 + r;
      int lm = l ? l-1 : LE-1;
      int lp = (l == LE-1) ? 0 : l+1;
      slot[r*SSL + lane] = (_Float16)(c0*serE[lm] + c1*serE[l] + c2*serE[lp] - cs);
    }
    WB();
    readA(slot, xa0, xa1, m, q);
    readC(slot, xc, m, q);
    // K tile
    f4 c[4];
    mm64r(xa0, xa1, eWk_t, c, m, q);
    #pragma unroll
    for (int nt = 0; nt < 4; ++nt){
      float bb = p.ebk[nt*16 + m];
      #pragma unroll
      for (int i = 0; i < 4; ++i)
        K[(r0 + q*4 + i)*SXE + nt*16 + m] = (_Float16)(c[nt][i] + bb);
    }
    // Vt tile
    mm64r(xa0, xa1, eWv_t, c, m, q);
    #pragma unroll
    for (int nt = 0; nt < 4; ++nt){
      float bb = p.ebv[nt*16 + m];
      h4 vv = { (_Float16)(c[nt][0]+bb), (_Float16)(c[nt][1]+bb),
                (_Float16)(c[nt][2]+bb), (_Float16)(c[nt][3]+bb) };
      *(h4*)(Vt + (nt*16+m)*SVT + r0 + q*4) = vv;
    }
  }
  __syncthreads();                       // B3: all K/V visible
  // ---- P3: enc attention + FFN (tile-local, regs) ----
  attn_reg(xa0, xa1, xc, slot, K, Vt, eWq_t, p.ebq, eWo_t, p.ebo,
           p.en1_g, p.en1_b, m, q);
  ffn_reg(xa0, xa1, xc, slot, ec1_t, p.ec1_b, ec2_t, p.ec2_b,
          p.en2_g, p.en2_b, m, q);
  __syncthreads();                       // B4: all attn reads of K/V done
  // ---- P4: dec cross K/V from enc_out (regs) ----
  {
    f4 c[4];
    mm64r(xa0, xa1, dWk_t, c, m, q);
    #pragma unroll
    for (int nt = 0; nt < 4; ++nt){
      float bb = p.dbk[nt*16 + m];
      #pragma unroll
      for (int i = 0; i < 4; ++i)
        K[(r0 + q*4 + i)*SXE + nt*16 + m] = (_Float16)(c[nt][i] + bb);
    }
    mm64r(xa0, xa1, dWv_t, c, m, q);
    #pragma unroll
    for (int nt = 0; nt < 4; ++nt){
      float bb = p.dbv[nt*16 + m];
      h4 vv = { (_Float16)(c[nt][0]+bb), (_Float16)(c[nt][1]+bb),
                (_Float16)(c[nt][2]+bb), (_Float16)(c[nt][3]+bb) };
      *(h4*)(Vt + (nt*16+m)*SVT + r0 + q*4) = vv;
    }
  }
  __syncthreads();                       // B5: dec K/V visible
  // ---- P5: decoder (waves 0-2 own dec tiles) ----
  if (wave < 3){
    // dec conv via slot -> regs (rows 96+r0 .. 96+r0+15; only left-edge rows <48 were mean-adj)
    {
      const float mu = stat[1];
      const float c0 = p.dec_conv_w[lane*3+0], c1 = p.dec_conv_w[lane*3+1], c2 = p.dec_conv_w[lane*3+2];
      #pragma unroll
      for (int r = 0; r < 16; ++r){
        int gr = 96 + r0 + r;
        float xl = serD[gr-1];
        float xm = serD[gr];
        float xr = (gr == LD-1) ? (serD[0] - mu) : serD[gr+1];
        slot[r*SSL + lane] = (_Float16)(c0*xl + c1*xm + c2*xr);
      }
      WB();
      readA(slot, xa0, xa1, m, q);
      readC(slot, xc, m, q);
    }
    attn_reg(xa0, xa1, xc, slot, K, Vt, dWq_t, p.dbq, dWo_t, p.dbo,
             p.dn2_g, p.dn2_b, m, q);
    // FFN d->4d->d, hidden chunked by 64; accumulate in C-layout regs
    f4 acc[4] = {{0.f,0.f,0.f,0.f},{0.f,0.f,0.f,0.f},{0.f,0.f,0.f,0.f},{0.f,0.f,0.f,0.f}};
    for (int cc = 0; cc < 4; ++cc){
      f4 h[4];
      mm64r(xa0, xa1, dc1t + cc*4096, h, m, q);
      float b1v[4];
      #pragma unroll
      for (int nt = 0; nt < 4; ++nt) b1v[nt] = p.dc1_b[cc*64 + nt*16 + m];
      storeC16(slot, h, b1v, true, m, q);
      WB();
      h8 ha0, ha1; readA(slot, ha0, ha1, m, q);
      #pragma unroll
      for (int nt = 0; nt < 4; ++nt){
        h8 b0 = *(const h8*)(dc2t + (nt*16+m)*256 + cc*64 + q*8);
        h8 b1 = *(const h8*)(dc2t + (nt*16+m)*256 + cc*64 + 32 + q*8);
        acc[nt] = MFMA16(ha0, b0, acc[nt]);
        acc[nt] = MFMA16(ha1, b1, acc[nt]);
      }
      WB();   // ha reads precede next cc's slot writes
    }
    // final LN(dn3) + proj + enc-mean
    float gvv[4], bvv[4], b2v[4], pwv[4];
    #pragma unroll
    for (int nt = 0; nt < 4; ++nt){
      int c = nt*16 + m;
      gvv[nt] = p.dn3_g[c]; bvv[nt] = p.dn3_b[c];
      b2v[nt] = p.dc2_b[c]; pwv[nt] = p.proj_w[c];
    }
    const float pb = p.proj_b[0], muE = stat[0];
    float vf[4][4];
    #pragma unroll
    for (int nt = 0; nt < 4; ++nt)
      #pragma unroll
      for (int i = 0; i < 4; ++i)
        vf[nt][i] = acc[nt][i] + b2v[nt] + (float)xc[nt][i];
    #pragma unroll
    for (int i = 0; i < 4; ++i){
      float s = red16_sum(vf[0][i] + vf[1][i] + vf[2][i] + vf[3][i]);
      float mu = s * (1.f/64.f);
      float d0 = vf[0][i]-mu, d1 = vf[1][i]-mu, d2 = vf[2][i]-mu, d3 = vf[3][i]-mu;
      float vv = red16_sum(d0*d0 + d1*d1 + d2*d2 + d3*d3);
      float rs = rsqrtf(vv * (1.f/64.f) + 1e-5f);
      float pp = (d0*rs*gvv[0] + bvv[0])*pwv[0] + (d1*rs*gvv[1] + bvv[1])*pwv[1]
               + (d2*rs*gvv[2] + bvv[2])*pwv[2] + (d3*rs*gvv[3] + bvv[3])*pwv[3];
      pp = red16_sum(pp);
      if (m == 0)
        p.out[(b*OUTL + r0 + q*4 + i)*NNODE + n] = pp + pb + muE;
    }
  }
}

extern "C" void kernel_launch(void* const* d_in, const int* in_sizes, int n_in,
                              void* d_out, int out_size, void* d_ws, size_t ws_size,
                              hipStream_t stream) {
  Params p;
  p.x_enc = (const float*)d_in[0];  p.x_dec = (const float*)d_in[1];
  p.enc_conv_w = (const float*)d_in[4];  p.dec_conv_w = (const float*)d_in[5];
  p.eWq = (const float*)d_in[6];   p.ebq = (const float*)d_in[7];
  p.eWk = (const float*)d_in[8];   p.ebk = (const float*)d_in[9];
  p.eWv = (const float*)d_in[10];  p.ebv = (const float*)d_in[11];
  p.eWo = (const float*)d_in[12];  p.ebo = (const float*)d_in[13];
  p.ec1_w = (const float*)d_in[14]; p.ec1_b = (const float*)d_in[15];
  p.ec2_w = (const float*)d_in[16]; p.ec2_b = (const float*)d_in[17];
  p.en1_g = (const float*)d_in[18]; p.en1_b = (const float*)d_in[19];
  p.en2_g = (const float*)d_in[20]; p.en2_b = (const float*)d_in[21];
  p.dWq = (const float*)d_in[22];  p.dbq = (const float*)d_in[23];
  p.dWk = (const float*)d_in[24];  p.dbk = (const float*)d_in[25];
  p.dWv = (const float*)d_in[26];  p.dbv = (const float*)d_in[27];
  p.dWo = (const float*)d_in[28];  p.dbo = (const float*)d_in[29];
  p.dc1_w = (const float*)d_in[30]; p.dc1_b = (const float*)d_in[31];
  p.dc2_w = (const float*)d_in[32]; p.dc2_b = (const float*)d_in[33];
  p.dn2_g = (const float*)d_in[34]; p.dn2_b = (const float*)d_in[35];
  p.dn3_g = (const float*)d_in[36]; p.dn3_b = (const float*)d_in[37];
  p.proj_w = (const float*)d_in[38]; p.proj_b = (const float*)d_in[39];
  p.out = (float*)d_out;

  _Float16* ws = (_Float16*)d_ws;
  prep_weights<<<144, 512, 0, stream>>>(p, ws);
  GraphTransformer_90237262889124_kernel<<<NSEQ, NTHR, 0, stream>>>(p, ws);
}